// Round 1
// baseline (1813.666 us; speedup 1.0000x reference)
//
#include <hip/hip_runtime.h>

#define DIV_UP(a,b) (((a)+(b)-1)/(b))

// ---------- ordered-uint float max keys ----------
__device__ __forceinline__ unsigned f2key(float f) {
  unsigned u = __float_as_uint(f);
  return (u & 0x80000000u) ? ~u : (u | 0x80000000u);
}
__device__ __forceinline__ float key2f(unsigned u) {
  unsigned b = (u & 0x80000000u) ? (u ^ 0x80000000u) : ~u;
  return __uint_as_float(b);
}

// ---------- utility ----------
__global__ void k_zero(int* p, int n) {
  int i = blockIdx.x * blockDim.x + threadIdx.x;
  if (i < n) p[i] = 0;
}

// ---------- degree count ----------
__global__ void k_count(const int* __restrict__ row, int* __restrict__ cnt, int E) {
  int e = blockIdx.x * blockDim.x + threadIdx.x;
  if (e < E) atomicAdd(&cnt[row[e]], 1);
}

// dis[i] = deg>0 ? rsqrt(deg) : 0
__global__ void k_dis(const int* __restrict__ cnt, float* __restrict__ dis, int N) {
  int i = blockIdx.x * blockDim.x + threadIdx.x;
  if (i < N) {
    int c = cnt[i];
    dis[i] = (c > 0) ? rsqrtf((float)c) : 0.0f;
  }
}

// ---------- 3-kernel exclusive scan over cnt -> rowptr ----------
__global__ void k_scan1(const int* __restrict__ cnt, int* __restrict__ incl,
                        int* __restrict__ bsum, int N) {
  __shared__ int s[1024];
  int t = threadIdx.x;
  int i = blockIdx.x * 1024 + t;
  int v = (i < N) ? cnt[i] : 0;
  s[t] = v;
  __syncthreads();
  for (int off = 1; off < 1024; off <<= 1) {
    int add = (t >= off) ? s[t - off] : 0;
    __syncthreads();
    s[t] += add;
    __syncthreads();
  }
  if (i < N) incl[i] = s[t];
  if (t == 1023) bsum[blockIdx.x] = s[1023];
}

__global__ void k_scan2(const int* __restrict__ bsum, int* __restrict__ bex, int nb) {
  if (threadIdx.x == 0) {
    int run = 0;
    for (int b = 0; b < nb; ++b) { bex[b] = run; run += bsum[b]; }
  }
}

__global__ void k_scan3(const int* __restrict__ incl, const int* __restrict__ cnt,
                        const int* __restrict__ bex, int* __restrict__ rowptr,
                        int* __restrict__ cursor, int N, int E) {
  int i = blockIdx.x * blockDim.x + threadIdx.x;
  if (i < N) {
    int v = incl[i] - cnt[i] + bex[i >> 10];
    rowptr[i] = v;
    cursor[i] = v;
  }
  if (i == 0) rowptr[N] = E;
}

// ---------- CSR fill: csr_col / csr_w (= norm) ----------
__global__ void k_fill(const int* __restrict__ row, const int* __restrict__ col,
                       const float* __restrict__ dis, int* __restrict__ cursor,
                       int* __restrict__ csr_col, float* __restrict__ csr_w, int E) {
  int e = blockIdx.x * blockDim.x + threadIdx.x;
  if (e >= E) return;
  int r = row[e], c = col[e];
  int idx = atomicAdd(&cursor[r], 1);
  csr_col[idx] = c;
  csr_w[idx] = -dis[r] * dis[c];
}

// ---------- prop: one wave per row, lane = feature ----------
// CHEB2: out = 2*prop(z) - tx0; else out = prop(z)
template <bool CHEB2>
__global__ void k_prop(const int* __restrict__ rowptr, const int* __restrict__ csr_col,
                       const float* __restrict__ csr_w, const float* __restrict__ z,
                       const float* __restrict__ tx0, float* __restrict__ out, int N) {
  int n = blockIdx.x * 4 + (threadIdx.x >> 6);
  int lane = threadIdx.x & 63;
  if (n >= N) return;
  int beg = rowptr[n], end = rowptr[n + 1];
  float acc = 0.0f;
  for (int j = beg; j < end; ++j) {
    int c = csr_col[j];
    float w = csr_w[j];
    acc += w * z[c * 64 + lane];
  }
  if (CHEB2)
    out[n * 64 + lane] = 2.0f * acc - tx0[n * 64 + lane];
  else
    out[n * 64 + lane] = acc;
}

// ---------- GEMM: out[n,h] = bias[h] + sum_k sum_d t_k[n,d]*W[k,d,h] ----------
template <int KK, bool ACC>
__global__ __launch_bounds__(256) void k_gemm(const float* __restrict__ t0,
                                              const float* __restrict__ t1,
                                              const float* __restrict__ t2,
                                              const float* __restrict__ W,
                                              const float* __restrict__ bias,
                                              float* __restrict__ out, int N) {
  __shared__ float w_s[KK * 64 * 64];
  __shared__ float b_s[64];
  for (int i = threadIdx.x; i < KK * 4096; i += 256) w_s[i] = W[i];
  if (threadIdx.x < 64) b_s[threadIdx.x] = bias[threadIdx.x];
  __syncthreads();
  int lane = threadIdx.x & 63;
  int wid = threadIdx.x >> 6;
  const float* ts[3] = {t0, t1, t2};
  for (int n = blockIdx.x * 4 + wid; n < N; n += gridDim.x * 4) {
    float acc = b_s[lane];
#pragma unroll
    for (int k = 0; k < KK; ++k) {
      const float4* rp = (const float4*)(ts[k] + (size_t)n * 64);
      const float* wk = w_s + k * 4096;
#pragma unroll
      for (int q = 0; q < 16; ++q) {
        float4 v = rp[q];
        acc += v.x * wk[(4 * q + 0) * 64 + lane];
        acc += v.y * wk[(4 * q + 1) * 64 + lane];
        acc += v.z * wk[(4 * q + 2) * 64 + lane];
        acc += v.w * wk[(4 * q + 3) * 64 + lane];
      }
    }
    if (ACC)
      out[(size_t)n * 64 + lane] += acc;
    else
      out[(size_t)n * 64 + lane] = acc;
  }
}

// ---------- BN stats: per-column sum / sumsq ----------
__global__ void k_bnstats(const float* __restrict__ X, float* __restrict__ sums,
                          float* __restrict__ sumsq, int N) {
  int lane = threadIdx.x & 63;
  int wid = threadIdx.x >> 6;
  float s = 0.0f, s2 = 0.0f;
  for (int n = blockIdx.x * 4 + wid; n < N; n += gridDim.x * 4) {
    float v = X[(size_t)n * 64 + lane];
    s += v;
    s2 += v * v;
  }
  __shared__ float ls[4][64], ls2[4][64];
  ls[wid][lane] = s;
  ls2[wid][lane] = s2;
  __syncthreads();
  if (threadIdx.x < 64) {
    float a = ls[0][lane] + ls[1][lane] + ls[2][lane] + ls[3][lane];
    float b = ls2[0][lane] + ls2[1][lane] + ls2[2][lane] + ls2[3][lane];
    atomicAdd(&sums[lane], a);
    atomicAdd(&sumsq[lane], b);
  }
}

__global__ void k_bncoef(const float* __restrict__ sums, const float* __restrict__ sumsq,
                         const float* __restrict__ g, const float* __restrict__ be,
                         float* __restrict__ scale, float* __restrict__ shift, int N) {
  int h = threadIdx.x;
  if (h >= 64) return;
  float inv_n = 1.0f / (float)N;
  float mu = sums[h] * inv_n;
  float var = sumsq[h] * inv_n - mu * mu;
  float sc = g[h] * rsqrtf(var + 1e-5f);
  scale[h] = sc;
  shift[h] = be[h] - mu * sc;
}

// ---------- BN apply + LeakyReLU (float4) ----------
__global__ void k_bnapply(const float* __restrict__ X, const float* __restrict__ scale,
                          const float* __restrict__ shift, float* __restrict__ Y,
                          int total4) {
  int i = blockIdx.x * blockDim.x + threadIdx.x;
  if (i >= total4) return;
  int h = (i * 4) & 63;
  float4 v = ((const float4*)X)[i];
  float a, b, c, d;
  a = v.x * scale[h + 0] + shift[h + 0];
  b = v.y * scale[h + 1] + shift[h + 1];
  c = v.z * scale[h + 2] + shift[h + 2];
  d = v.w * scale[h + 3] + shift[h + 3];
  v.x = (a > 0.0f) ? a : 0.01f * a;
  v.y = (b > 0.0f) ? b : 0.01f * b;
  v.z = (c > 0.0f) ? c : 0.01f * c;
  v.w = (d > 0.0f) ? d : 0.01f * d;
  ((float4*)Y)[i] = v;
}

// ---------- pooling ----------
__global__ void k_poolinit(unsigned* __restrict__ pooled, int n) {
  int i = blockIdx.x * blockDim.x + threadIdx.x;
  if (i < n) pooled[i] = 0x007FFFFFu;  // key(-inf)
}

// block handles 64 consecutive rows; batch is sorted -> run compression
__global__ void k_pool(const float* __restrict__ X, const int* __restrict__ batch,
                       unsigned* __restrict__ pooled, int N) {
  int t = threadIdx.x;
  int h = t & 63;
  int rsub = t >> 6;
  int base = blockIdx.x * 64;
  int cur_g = -1;
  unsigned best = 0;
  for (int i = 0; i < 16; ++i) {
    int n = base + rsub + 4 * i;
    if (n >= N) break;
    int g = batch[n];
    unsigned k = f2key(X[(size_t)n * 64 + h]);
    if (g != cur_g) {
      if (cur_g >= 0) atomicMax(&pooled[cur_g * 64 + h], best);
      cur_g = g;
      best = k;
    } else {
      best = max(best, k);
    }
  }
  if (cur_g >= 0) atomicMax(&pooled[cur_g * 64 + h], best);
}

// ---------- final: out[g] = sum_h pooled[g,h]*w_lin[h] + b_lin ----------
__global__ void k_final(const unsigned* __restrict__ pooled, const float* __restrict__ w_lin,
                        const float* __restrict__ b_lin, float* __restrict__ out) {
  int g = blockIdx.x;
  int h = threadIdx.x;
  float v = key2f(pooled[g * 64 + h]) * w_lin[h];
  for (int off = 32; off > 0; off >>= 1) v += __shfl_down(v, off, 64);
  if (h == 0) out[g] = v + b_lin[0];
}

extern "C" void kernel_launch(void* const* d_in, const int* in_sizes, int n_in,
                              void* d_out, int out_size, void* d_ws, size_t ws_size,
                              hipStream_t stream) {
  const float* x = (const float*)d_in[0];
  const int* ei = (const int*)d_in[1];
  const int* batch = (const int*)d_in[2];
  const float* w1 = (const float*)d_in[3];
  const float* b1 = (const float*)d_in[4];
  const float* w2 = (const float*)d_in[5];
  const float* b2 = (const float*)d_in[6];
  const float* w3 = (const float*)d_in[7];
  const float* b3 = (const float*)d_in[8];
  const float* g1 = (const float*)d_in[9];
  const float* be1 = (const float*)d_in[10];
  const float* g2 = (const float*)d_in[11];
  const float* be2 = (const float*)d_in[12];
  const float* g3 = (const float*)d_in[13];
  const float* be3 = (const float*)d_in[14];
  const float* w_sc = (const float*)d_in[15];
  const float* b_sc = (const float*)d_in[16];
  const float* w_lin = (const float*)d_in[17];
  const float* b_lin = (const float*)d_in[18];

  int N = in_sizes[0] / 64;
  int E = in_sizes[1] / 2;
  int G = out_size;
  const int* row = ei;
  const int* col = ei + E;

  // workspace carve (256B aligned)
  char* p = (char*)d_ws;
  auto carve = [&](size_t bytes) -> void* {
    void* r = (void*)p;
    p += (bytes + 255) & ~(size_t)255;
    return r;
  };
  int* cnt = (int*)carve((size_t)N * 4);
  float* dis = (float*)carve((size_t)N * 4);
  int* rowptr = (int*)carve((size_t)(N + 1) * 4);
  int* cursor = (int*)carve((size_t)N * 4);
  int* incl = (int*)carve((size_t)N * 4);
  int* bsum = (int*)carve(1024);
  int* bex = (int*)carve(1024);
  int* csr_col = (int*)carve((size_t)E * 4);
  float* csr_w = (float*)carve((size_t)E * 4);
  float* A = (float*)carve((size_t)N * 64 * 4);
  float* B = (float*)carve((size_t)N * 64 * 4);
  float* C = (float*)carve((size_t)N * 64 * 4);
  float* Dh = (float*)carve((size_t)N * 64 * 4);
  float* stats = (float*)carve(256 * 4);  // sums|sumsq|scale|shift
  unsigned* pooled = (unsigned*)carve((size_t)G * 64 * 4);

  // ---- graph structure (once per call) ----
  k_zero<<<DIV_UP(N, 256), 256, 0, stream>>>(cnt, N);
  k_count<<<DIV_UP(E, 256), 256, 0, stream>>>(row, cnt, E);
  k_dis<<<DIV_UP(N, 256), 256, 0, stream>>>(cnt, dis, N);
  int nb = DIV_UP(N, 1024);
  k_scan1<<<nb, 1024, 0, stream>>>(cnt, incl, bsum, N);
  k_scan2<<<1, 64, 0, stream>>>(bsum, bex, nb);
  k_scan3<<<DIV_UP(N, 256), 256, 0, stream>>>(incl, cnt, bex, rowptr, cursor, N, E);
  k_fill<<<DIV_UP(E, 256), 256, 0, stream>>>(row, col, dis, cursor, csr_col, csr_w, E);

  const float* Ws[3] = {w1, w2, w3};
  const float* bs[3] = {b1, b2, b3};
  const float* gs[3] = {g1, g2, g3};
  const float* bes[3] = {be1, be2, be3};

  const float* tx0 = x;
  for (int l = 0; l < 3; ++l) {
    k_prop<false><<<DIV_UP(N, 4), 256, 0, stream>>>(rowptr, csr_col, csr_w, tx0, nullptr, A, N);
    k_prop<true><<<DIV_UP(N, 4), 256, 0, stream>>>(rowptr, csr_col, csr_w, A, tx0, B, N);
    k_gemm<3, false><<<2048, 256, 0, stream>>>(tx0, A, B, Ws[l], bs[l], C, N);
    k_zero<<<1, 256, 0, stream>>>((int*)stats, 128);
    k_bnstats<<<1024, 256, 0, stream>>>(C, stats, stats + 64, N);
    k_bncoef<<<1, 64, 0, stream>>>(stats, stats + 64, gs[l], bes[l], stats + 128, stats + 192, N);
    k_bnapply<<<DIV_UP(N * 16, 256), 256, 0, stream>>>(C, stats + 128, stats + 192, Dh, N * 16);
    tx0 = Dh;
  }
  // shortcut: Dh += x @ w_sc + b_sc
  k_gemm<1, true><<<2048, 256, 0, stream>>>(x, nullptr, nullptr, w_sc, b_sc, Dh, N);

  k_poolinit<<<DIV_UP(G * 64, 256), 256, 0, stream>>>(pooled, G * 64);
  k_pool<<<DIV_UP(N, 64), 256, 0, stream>>>(Dh, batch, pooled, N);
  k_final<<<G, 64, 0, stream>>>(pooled, w_lin, b_lin, (float*)d_out);
}